// Round 7
// baseline (263.001 us; speedup 1.0000x reference)
//
#include <hip/hip_runtime.h>
#include <math.h>

#define DIM     4096
#define NEXP    64
#define TOPK_N  8
#define TAU     2.0e-4f
#define TGB     64                  // tokens per gemm block (4 waves x 16)
#define KC      512                 // k-chunk per gemm block
#define NKC     (DIM / KC)          // 8 chunks
#define KS32    (KC / 32)           // 16 k32 steps per chunk

#define WS_WHI_OFF  0
#define WS_WLO_OFF  (512*1024)
#define WS_PART_OFF (1024*1024)     // optional fp32 [ntok][NKC][NEXP] = 16 MB

typedef __attribute__((ext_vector_type(8))) short short8;   // 8 bf16
typedef __attribute__((ext_vector_type(4))) float f32x4;

#define WALL __builtin_amdgcn_sched_barrier(0)

// fp32 -> bf16 hi (trunc) + bf16 lo (trunc of exact residual)
__device__ __forceinline__ void cvt8(float4 a0, float4 a1, short8& hv, short8& lv) {
    float f[8] = {a0.x, a0.y, a0.z, a0.w, a1.x, a1.y, a1.z, a1.w};
    union { short8 v; unsigned u[4]; } H, L;
    #pragma unroll
    for (int i = 0; i < 4; ++i) {
        unsigned b0 = __float_as_uint(f[2*i]);
        unsigned b1 = __float_as_uint(f[2*i+1]);
        float r0 = f[2*i]   - __uint_as_float(b0 & 0xffff0000u);
        float r1 = f[2*i+1] - __uint_as_float(b1 & 0xffff0000u);
        H.u[i] = (b0 >> 16) | (b1 & 0xffff0000u);
        L.u[i] = (__float_as_uint(r0) >> 16) | (__float_as_uint(r1) & 0xffff0000u);
    }
    hv = H.v; lv = L.v;
}

// ---------------- Pass 0a: w fp32 -> bf16 hi/lo ----------------
__global__ __launch_bounds__(256, 4)
void cvt_w_kernel(const float* __restrict__ w, unsigned short* __restrict__ whi,
                  unsigned short* __restrict__ wlo) {
    const int g = blockIdx.x * 256 + threadIdx.x;
    const float* p = w + (size_t)g * 8;
    union { short8 v; uint4 q; } H, L;
    float4 a0 = *(const float4*)(p);
    float4 a1 = *(const float4*)(p + 4);
    cvt8(a0, a1, H.v, L.v);
    *(uint4*)(whi + (size_t)g * 8) = H.q;
    *(uint4*)(wlo + (size_t)g * 8) = L.q;
}

// ---------------- Pass 0b (atomic mode only): zero the score accumulator ----------------
__global__ __launch_bounds__(256, 4)
void zero_kernel(float* __restrict__ p) {
    const size_t g = (size_t)blockIdx.x * 256 + threadIdx.x;
    *(float4*)(p + g * 4) = (float4){0.f, 0.f, 0.f, 0.f};
}

// ---------------- Pass 1: split-K partial GEMM (no LDS, no barriers) ----------------
// 1024 blocks x 256 thr (4 waves). Block = 64 tokens x 64 experts x k-chunk 512.
// Wave = 16 tokens x 64 experts, 16 k32 steps, fully independent streaming.
// B-traffic total = 128 MB (128 KB/block); kc == blockIdx%8 == XCD -> each XCD's L2
// holds exactly one B-chunk. USE_PART=1: deterministic partials to workspace.
// USE_PART=0: atomicAdd into the probs region of out (device-scope, m20).
template<int USE_PART>
__global__ __launch_bounds__(256, 4)
void gemm_part_kernel(const float* __restrict__ x, const unsigned short* __restrict__ whi,
                      const unsigned short* __restrict__ wlo, float* __restrict__ dst,
                      int ntok) {
    const int tid  = threadIdx.x;
    const int lane = tid & 63;
    const int wvm  = tid >> 6;
    const int nl   = lane & 15;
    const int q    = lane >> 4;
    const int kc   = blockIdx.x & (NKC - 1);
    const int tg   = blockIdx.x >> 3;
    const int t0   = tg * TGB + wvm * 16;
    const int k0   = kc * KC;

    const float* xr = x + (size_t)(t0 + nl) * DIM + k0;
    const unsigned short* bh[4];
    const unsigned short* bl[4];
    #pragma unroll
    for (int nf = 0; nf < 4; ++nf) {
        const size_t o = (size_t)(nf * 16 + nl) * DIM + k0;
        bh[nf] = whi + o;
        bl[nf] = wlo + o;
    }

    f32x4 acc[4];
    #pragma unroll
    for (int nf = 0; nf < 4; ++nf) acc[nf] = (f32x4){0.f, 0.f, 0.f, 0.f};

    float4 Ar[2][2];
    Ar[0][0] = *(const float4*)(xr + q * 8);
    Ar[0][1] = *(const float4*)(xr + q * 8 + 4);

    #pragma unroll 2
    for (int s = 0; s < KS32; ++s) {
        const int buf = s & 1;
        if (s + 1 < KS32) {   // prefetch next step's A
            const int kk = (s + 1) * 32 + q * 8;
            Ar[buf ^ 1][0] = *(const float4*)(xr + kk);
            Ar[buf ^ 1][1] = *(const float4*)(xr + kk + 4);
        }
        WALL;
        const int kk = s * 32 + q * 8;
        short8 bhv[4], blv[4];
        #pragma unroll
        for (int nf = 0; nf < 4; ++nf) {
            bhv[nf] = *(const short8*)(bh[nf] + kk);
            blv[nf] = *(const short8*)(bl[nf] + kk);
        }
        short8 ahi, alo;
        cvt8(Ar[buf][0], Ar[buf][1], ahi, alo);
        #pragma unroll
        for (int nf = 0; nf < 4; ++nf) {
            acc[nf] = __builtin_amdgcn_mfma_f32_16x16x32_bf16(ahi, blv[nf], acc[nf], 0, 0, 0);
            acc[nf] = __builtin_amdgcn_mfma_f32_16x16x32_bf16(alo, bhv[nf], acc[nf], 0, 0, 0);
            acc[nf] = __builtin_amdgcn_mfma_f32_16x16x32_bf16(ahi, bhv[nf], acc[nf], 0, 0, 0);
        }
        WALL;
    }

    // C/D layout (verified rounds 0-5): col = lane&15 -> expert, row = q*4+r -> token
    #pragma unroll
    for (int nf = 0; nf < 4; ++nf)
        #pragma unroll
        for (int r = 0; r < 4; ++r) {
            const int tok = t0 + q * 4 + r;
            const int e   = nf * 16 + nl;
            if (USE_PART)
                dst[((size_t)tok * NKC + kc) * NEXP + e] = acc[nf][r];
            else
                atomicAdd(&dst[(size_t)tok * NEXP + e], acc[nf][r]);
        }
}

// ---------------- Pass 2: reduce + softmax + top-8 + fp64 recheck (wave-local) ----------------
// 2048 blocks x 256 thr; wave = one token, lane = expert. No __syncthreads anywhere.
template<int USE_PART>
__global__ __launch_bounds__(256, 4)
void finish_kernel(const float* __restrict__ src, const float* __restrict__ bias,
                   const float* __restrict__ x, const float* __restrict__ wfp,
                   float* __restrict__ out, int ntok) {
    __shared__ float lds_s[4][68];   // per-wave score row (16B-aligned rows)
    __shared__ float t9[4][12];      // per-wave top-9

    const int tid  = threadIdx.x;
    const int lane = tid & 63;
    const int wv   = tid >> 6;
    const int tok  = blockIdx.x * 4 + wv;

    float s;
    if (USE_PART) {
        // fixed-order reduce of NKC chunk partials (deterministic)
        const float* pr = src + (size_t)tok * NKC * NEXP;
        s = pr[lane];
        #pragma unroll
        for (int c = 1; c < NKC; ++c) s += pr[c * NEXP + lane];
    } else {
        s = src[(size_t)tok * NEXP + lane];   // atomically accumulated score
    }
    s += bias[lane];

    // softmax (butterfly)
    float m = s;
    #pragma unroll
    for (int off = 32; off > 0; off >>= 1)
        m = fmaxf(m, __shfl_xor(m, off, 64));
    const float ex = expf(s - m);
    float sum = ex;
    #pragma unroll
    for (int off = 32; off > 0; off >>= 1)
        sum += __shfl_xor(sum, off, 64);
    out[(size_t)tok * NEXP + lane] = ex / sum;

    // parallel rank via wave-local LDS row (intra-wave lockstep, no barrier needed)
    lds_s[wv][lane] = s;
    int rank = 0;
    #pragma unroll
    for (int i = 0; i < 16; ++i) {
        const float4 v4 = *(const float4*)(&lds_s[wv][i * 4]);
        rank += (int)((v4.x > s) || (v4.x == s && (i * 4 + 0) < lane));
        rank += (int)((v4.y > s) || (v4.y == s && (i * 4 + 1) < lane));
        rank += (int)((v4.z > s) || (v4.z == s && (i * 4 + 2) < lane));
        rank += (int)((v4.w > s) || (v4.w == s && (i * 4 + 3) < lane));
    }
    float* __restrict__ out_idx = out + (size_t)ntok * NEXP;
    if (rank < TOPK_N + 1) t9[wv][rank] = s;
    if (rank < TOPK_N)
        out_idx[(size_t)tok * TOPK_N + rank] = (float)lane;

    // tie-screen on the 8 gaps of the top-9 (wave-local)
    float gap = 1e30f;
    if (lane < TOPK_N) gap = t9[wv][lane] - t9[wv][lane + 1];
    if (__any(gap < TAU)) {
        // fp64 recheck: candidates = scores >= 9th-best - TAU (deterministic result)
        const float thr = t9[wv][TOPK_N] - TAU;
        const unsigned long long cmask = __ballot(s >= thr);
        double dscv = -1.0e300;
        unsigned long long mm = cmask;
        while (mm) {
            const int e = __builtin_ctzll(mm);
            mm &= mm - 1;
            const float* wr  = wfp + (size_t)e * DIM;
            const float* xrr = x + (size_t)tok * DIM;
            double a = 0.0;
            #pragma unroll 4
            for (int kk = 0; kk < 16; ++kk) {
                const int k = kk * 256 + lane * 4;
                const float4 wv4 = *(const float4*)(wr + k);
                const float4 xv  = *(const float4*)(xrr + k);
                a = fma((double)xv.x, (double)wv4.x, a);
                a = fma((double)xv.y, (double)wv4.y, a);
                a = fma((double)xv.z, (double)wv4.z, a);
                a = fma((double)xv.w, (double)wv4.w, a);
            }
            #pragma unroll
            for (int off = 32; off > 0; off >>= 1)
                a += __shfl_xor(a, off, 64);   // sum lands on all lanes
            a += (double)bias[e];
            if (lane == e) dscv = a;           // non-candidates stay -1e300
        }
        // serial argmax top-8 by fp64 score (rare path)
        double cv = dscv;
        for (int r = 0; r < TOPK_N; ++r) {
            double bv = cv;
            int    bi = lane;
            #pragma unroll
            for (int off = 32; off > 0; off >>= 1) {
                const double ov = __shfl_xor(bv, off, 64);
                const int    oi = __shfl_xor(bi, off, 64);
                if (ov > bv || (ov == bv && oi < bi)) { bv = ov; bi = oi; }
            }
            if (lane == r)
                out_idx[(size_t)tok * TOPK_N + r] = (float)bi;
            if (lane == bi) cv = -1.0e301;
        }
    }
}

extern "C" void kernel_launch(void* const* d_in, const int* in_sizes, int n_in,
                              void* d_out, int out_size, void* d_ws, size_t ws_size,
                              hipStream_t stream) {
    const float* x  = (const float*)d_in[0];
    const float* w  = (const float*)d_in[1];
    const float* bs = (const float*)d_in[2];
    float* out = (float*)d_out;

    unsigned short* whi = (unsigned short*)((char*)d_ws + WS_WHI_OFF);
    unsigned short* wlo = (unsigned short*)((char*)d_ws + WS_WLO_OFF);

    const int ntok = in_sizes[0] / DIM;          // 8192

    hipLaunchKernelGGL(cvt_w_kernel, dim3((NEXP * DIM) / 8 / 256), dim3(256), 0, stream,
                       w, whi, wlo);

    const size_t part_need = (size_t)WS_PART_OFF + (size_t)ntok * NKC * NEXP * sizeof(float);
    if (ws_size >= part_need) {
        // deterministic split-K partials in workspace
        float* part = (float*)((char*)d_ws + WS_PART_OFF);
        hipLaunchKernelGGL((gemm_part_kernel<1>), dim3((ntok / TGB) * NKC), dim3(256), 0, stream,
                           x, whi, wlo, part, ntok);
        hipLaunchKernelGGL((finish_kernel<1>), dim3(ntok / 4), dim3(256), 0, stream,
                           part, bs, x, w, out, ntok);
    } else {
        // workspace too small: accumulate scores atomically in out's probs region
        hipLaunchKernelGGL(zero_kernel, dim3((ntok * NEXP) / 1024), dim3(256), 0, stream, out);
        hipLaunchKernelGGL((gemm_part_kernel<0>), dim3((ntok / TGB) * NKC), dim3(256), 0, stream,
                           x, whi, wlo, out, ntok);
        hipLaunchKernelGGL((finish_kernel<0>), dim3(ntok / 4), dim3(256), 0, stream,
                           out, bs, x, w, out, ntok);
    }
}

// Round 8
// 228.403 us; speedup vs baseline: 1.1515x; 1.1515x over previous
//
#include <hip/hip_runtime.h>
#include <math.h>

#define DIM     4096
#define NEXP    64
#define TOPK_N  8
#define TAU     2.0e-4f
#define TGB     64                  // tokens per gemm block (4 waves x 16)
#define KC      512                 // k-chunk per gemm block
#define NKC     (DIM / KC)          // 8 chunks
#define NST     (KC / 32)           // 16 k32 subtiles per chunk

#define WS_WHI_OFF  0
#define WS_WLO_OFF  (512*1024)
#define WS_PART_OFF (1024*1024)     // optional fp32 [ntok][NKC][NEXP] = 16 MB

typedef __attribute__((ext_vector_type(8))) short short8;   // 8 bf16
typedef __attribute__((ext_vector_type(4))) float f32x4;

#define WALL __builtin_amdgcn_sched_barrier(0)

// fp32 -> bf16 hi (trunc) + bf16 lo (trunc of exact residual)
__device__ __forceinline__ void cvt8(float4 a0, float4 a1, short8& hv, short8& lv) {
    float f[8] = {a0.x, a0.y, a0.z, a0.w, a1.x, a1.y, a1.z, a1.w};
    union { short8 v; unsigned u[4]; } H, L;
    #pragma unroll
    for (int i = 0; i < 4; ++i) {
        unsigned b0 = __float_as_uint(f[2*i]);
        unsigned b1 = __float_as_uint(f[2*i+1]);
        float r0 = f[2*i]   - __uint_as_float(b0 & 0xffff0000u);
        float r1 = f[2*i+1] - __uint_as_float(b1 & 0xffff0000u);
        H.u[i] = (b0 >> 16) | (b1 & 0xffff0000u);
        L.u[i] = (__float_as_uint(r0) >> 16) | (__float_as_uint(r1) & 0xffff0000u);
    }
    hv = H.v; lv = L.v;
}

// async global->LDS, 16B per lane; LDS dest = wave-uniform base + lane*16 (linear);
// global source address is fully per-lane.
__device__ __forceinline__ void async16(void* lds, const void* g) {
    __builtin_amdgcn_global_load_lds(
        (const __attribute__((address_space(1))) unsigned int*)g,
        (__attribute__((address_space(3))) unsigned int*)lds, 16, 0, 0);
}

// ---------------- Pass 0a: w fp32 -> bf16 hi/lo ----------------
__global__ __launch_bounds__(256, 4)
void cvt_w_kernel(const float* __restrict__ w, unsigned short* __restrict__ whi,
                  unsigned short* __restrict__ wlo) {
    const int g = blockIdx.x * 256 + threadIdx.x;
    const float* p = w + (size_t)g * 8;
    union { short8 v; uint4 q; } H, L;
    float4 a0 = *(const float4*)(p);
    float4 a1 = *(const float4*)(p + 4);
    cvt8(a0, a1, H.v, L.v);
    *(uint4*)(whi + (size_t)g * 8) = H.q;
    *(uint4*)(wlo + (size_t)g * 8) = L.q;
}

// ---------------- Pass 0b (atomic mode only): zero the score accumulator ----------------
__global__ __launch_bounds__(256, 4)
void zero_kernel(float* __restrict__ p) {
    const size_t g = (size_t)blockIdx.x * 256 + threadIdx.x;
    *(float4*)(p + g * 4) = (float4){0.f, 0.f, 0.f, 0.f};
}

// ---------------- Pass 1: split-K GEMM, fully LDS-staged via global_load_lds ----------------
// 1024 blocks x 256 thr (4 waves). Block = 64 tokens x 64 experts x k-chunk 512.
// ALL steady-state bytes go global->LDS (bypasses the ~10 B/cyc/CU global->VGPR ceiling
// that pinned rounds 0-7). Per k32 subtile: A_lds[64][32]f32 (rows 128B) + B_lds[64][64]bf16
// (row = 64B hi | 64B lo, 128B). XOR swizzle (row&7)<<4 applied to gll SOURCE and ds_read
// (both-sides involution); per-read slot distribution is uniform -> no excess conflicts.
// hi/lo source select is per-lane (gll global addr is per-lane). Numerics identical to R7.
template<int USE_PART>
__global__ __launch_bounds__(256, 4)
void gemm_part_kernel(const float* __restrict__ x, const unsigned short* __restrict__ whi,
                      const unsigned short* __restrict__ wlo, float* __restrict__ dst,
                      int ntok) {
    __shared__ float          A_lds[2][TGB][32];    // 2 x 8 KB
    __shared__ unsigned short B_lds[2][NEXP][64];   // 2 x 8 KB

    const int tid  = threadIdx.x;
    const int lane = tid & 63;
    const int wv   = tid >> 6;
    const int nl   = lane & 15;
    const int q    = lane >> 4;
    const int kc   = blockIdx.x & (NKC - 1);
    const int tg   = blockIdx.x >> 3;
    const int t0b  = tg * TGB;
    const int k0   = kc * KC;

    // --- per-lane staging constants: each wave issues 2 A-insts + 2 B-insts per subtile.
    // Inst covers 1 KB = 8 rows of 128 B. Dest linear; source pre-XOR'd with row swizzle.
    int arow[2], brow[2];
    const float* gA[2];
    const unsigned short* gB[2];
    #pragma unroll
    for (int i = 0; i < 2; ++i) {
        const int inst = wv * 2 + i;
        {   // A: row r holds x[t0b+r][k0+st*32 .. +32] (fp32, 128 B)
            const int r   = inst * 8 + (lane >> 3);
            const int scb = ((lane & 7) * 16) ^ ((r & 7) << 4);
            arow[i] = inst * 8;
            gA[i] = x + (size_t)(t0b + r) * DIM + k0 + (scb >> 2);
        }
        {   // B: row e = [hi k32 (64B) | lo k32 (64B)]; swizzle can swap halves -> per-lane sel
            const int e   = inst * 8 + (lane >> 3);
            const int scb = ((lane & 7) * 16) ^ ((e & 7) << 4);
            brow[i] = inst * 8;
            const unsigned short* base = (scb & 64) ? wlo : whi;
            gB[i] = base + (size_t)e * DIM + k0 + ((scb & 63) >> 1);
        }
    }

    f32x4 acc[4];
    #pragma unroll
    for (int nf = 0; nf < 4; ++nf) acc[nf] = (f32x4){0.f, 0.f, 0.f, 0.f};

#define STAGE(b_, st_) do {                                                    \
        async16(&A_lds[b_][arow[0]][0], gA[0] + (st_) * 32);                   \
        async16(&A_lds[b_][arow[1]][0], gA[1] + (st_) * 32);                   \
        async16(&B_lds[b_][brow[0]][0], gB[0] + (st_) * 32);                   \
        async16(&B_lds[b_][brow[1]][0], gB[1] + (st_) * 32);                   \
    } while (0)

#define COMPUTE(b_) do {                                                       \
        const char* Ab_ = (const char*)&A_lds[b_][wv * 16 + nl][0];            \
        const int swz_ = (nl & 7) << 4;                                        \
        float4 a0_ = *(const float4*)(Ab_ + ((q * 32) ^ swz_));                \
        float4 a1_ = *(const float4*)(Ab_ + ((q * 32 + 16) ^ swz_));           \
        short8 ahi_, alo_;                                                     \
        cvt8(a0_, a1_, ahi_, alo_);                                            \
        _Pragma("unroll")                                                      \
        for (int nf_ = 0; nf_ < 4; ++nf_) {                                    \
            const char* Bb_ = (const char*)&B_lds[b_][nf_ * 16 + nl][0];       \
            short8 bh_ = *(const short8*)(Bb_ + ((q * 16) ^ swz_));            \
            short8 bl_ = *(const short8*)(Bb_ + ((64 + q * 16) ^ swz_));       \
            acc[nf_] = __builtin_amdgcn_mfma_f32_16x16x32_bf16(ahi_, bl_, acc[nf_], 0, 0, 0); \
            acc[nf_] = __builtin_amdgcn_mfma_f32_16x16x32_bf16(alo_, bh_, acc[nf_], 0, 0, 0); \
            acc[nf_] = __builtin_amdgcn_mfma_f32_16x16x32_bf16(ahi_, bh_, acc[nf_], 0, 0, 0); \
        }                                                                      \
    } while (0)

    STAGE(0, 0);
    __syncthreads();
    #pragma unroll 2
    for (int st = 0; st < NST; ++st) {
        const int b = st & 1;
        if (st + 1 < NST) STAGE(b ^ 1, st + 1);   // fire-and-forget next subtile
        WALL;                                      // keep issue before compute
        COMPUTE(b);
        __syncthreads();                           // drain overlapped with compute
    }

#undef STAGE
#undef COMPUTE

    // C/D layout (verified): col = lane&15 -> expert, row = q*4+r -> token-in-wave-group
    #pragma unroll
    for (int nf = 0; nf < 4; ++nf)
        #pragma unroll
        for (int r = 0; r < 4; ++r) {
            const int tok = t0b + wv * 16 + q * 4 + r;
            const int e   = nf * 16 + nl;
            if (USE_PART)
                dst[((size_t)tok * NKC + kc) * NEXP + e] = acc[nf][r];
            else
                atomicAdd(&dst[(size_t)tok * NEXP + e], acc[nf][r]);
        }
}

// ---------------- Pass 2: reduce + softmax + top-8 + fp64 recheck (wave-local) ----------------
// 2048 blocks x 256 thr; wave = one token, lane = expert. No __syncthreads anywhere.
template<int USE_PART>
__global__ __launch_bounds__(256, 4)
void finish_kernel(const float* __restrict__ src, const float* __restrict__ bias,
                   const float* __restrict__ x, const float* __restrict__ wfp,
                   float* __restrict__ out, int ntok) {
    __shared__ float lds_s[4][68];   // per-wave score row (16B-aligned rows)
    __shared__ float t9[4][12];      // per-wave top-9

    const int tid  = threadIdx.x;
    const int lane = tid & 63;
    const int wv   = tid >> 6;
    const int tok  = blockIdx.x * 4 + wv;

    float s;
    if (USE_PART) {
        // fixed-order reduce of NKC chunk partials (deterministic)
        const float* pr = src + (size_t)tok * NKC * NEXP;
        s = pr[lane];
        #pragma unroll
        for (int c = 1; c < NKC; ++c) s += pr[c * NEXP + lane];
    } else {
        s = src[(size_t)tok * NEXP + lane];   // atomically accumulated score
    }
    s += bias[lane];

    // softmax (butterfly)
    float m = s;
    #pragma unroll
    for (int off = 32; off > 0; off >>= 1)
        m = fmaxf(m, __shfl_xor(m, off, 64));
    const float ex = expf(s - m);
    float sum = ex;
    #pragma unroll
    for (int off = 32; off > 0; off >>= 1)
        sum += __shfl_xor(sum, off, 64);
    out[(size_t)tok * NEXP + lane] = ex / sum;

    // parallel rank via wave-local LDS row (intra-wave lockstep, no barrier needed)
    lds_s[wv][lane] = s;
    int rank = 0;
    #pragma unroll
    for (int i = 0; i < 16; ++i) {
        const float4 v4 = *(const float4*)(&lds_s[wv][i * 4]);
        rank += (int)((v4.x > s) || (v4.x == s && (i * 4 + 0) < lane));
        rank += (int)((v4.y > s) || (v4.y == s && (i * 4 + 1) < lane));
        rank += (int)((v4.z > s) || (v4.z == s && (i * 4 + 2) < lane));
        rank += (int)((v4.w > s) || (v4.w == s && (i * 4 + 3) < lane));
    }
    float* __restrict__ out_idx = out + (size_t)ntok * NEXP;
    if (rank < TOPK_N + 1) t9[wv][rank] = s;
    if (rank < TOPK_N)
        out_idx[(size_t)tok * TOPK_N + rank] = (float)lane;

    // tie-screen on the 8 gaps of the top-9 (wave-local)
    float gap = 1e30f;
    if (lane < TOPK_N) gap = t9[wv][lane] - t9[wv][lane + 1];
    if (__any(gap < TAU)) {
        // fp64 recheck: candidates = scores >= 9th-best - TAU (deterministic result)
        const float thr = t9[wv][TOPK_N] - TAU;
        const unsigned long long cmask = __ballot(s >= thr);
        double dscv = -1.0e300;
        unsigned long long mm = cmask;
        while (mm) {
            const int e = __builtin_ctzll(mm);
            mm &= mm - 1;
            const float* wr  = wfp + (size_t)e * DIM;
            const float* xrr = x + (size_t)tok * DIM;
            double a = 0.0;
            #pragma unroll 4
            for (int kk = 0; kk < 16; ++kk) {
                const int k = kk * 256 + lane * 4;
                const float4 wv4 = *(const float4*)(wr + k);
                const float4 xv  = *(const float4*)(xrr + k);
                a = fma((double)xv.x, (double)wv4.x, a);
                a = fma((double)xv.y, (double)wv4.y, a);
                a = fma((double)xv.z, (double)wv4.z, a);
                a = fma((double)xv.w, (double)wv4.w, a);
            }
            #pragma unroll
            for (int off = 32; off > 0; off >>= 1)
                a += __shfl_xor(a, off, 64);   // sum lands on all lanes
            a += (double)bias[e];
            if (lane == e) dscv = a;           // non-candidates stay -1e300
        }
        // serial argmax top-8 by fp64 score (rare path)
        double cv = dscv;
        for (int r = 0; r < TOPK_N; ++r) {
            double bv = cv;
            int    bi = lane;
            #pragma unroll
            for (int off = 32; off > 0; off >>= 1) {
                const double ov = __shfl_xor(bv, off, 64);
                const int    oi = __shfl_xor(bi, off, 64);
                if (ov > bv || (ov == bv && oi < bi)) { bv = ov; bi = oi; }
            }
            if (lane == r)
                out_idx[(size_t)tok * TOPK_N + r] = (float)bi;
            if (lane == bi) cv = -1.0e301;
        }
    }
}

extern "C" void kernel_launch(void* const* d_in, const int* in_sizes, int n_in,
                              void* d_out, int out_size, void* d_ws, size_t ws_size,
                              hipStream_t stream) {
    const float* x  = (const float*)d_in[0];
    const float* w  = (const float*)d_in[1];
    const float* bs = (const float*)d_in[2];
    float* out = (float*)d_out;

    unsigned short* whi = (unsigned short*)((char*)d_ws + WS_WHI_OFF);
    unsigned short* wlo = (unsigned short*)((char*)d_ws + WS_WLO_OFF);

    const int ntok = in_sizes[0] / DIM;          // 8192

    hipLaunchKernelGGL(cvt_w_kernel, dim3((NEXP * DIM) / 8 / 256), dim3(256), 0, stream,
                       w, whi, wlo);

    const size_t part_need = (size_t)WS_PART_OFF + (size_t)ntok * NKC * NEXP * sizeof(float);
    if (ws_size >= part_need) {
        // deterministic split-K partials in workspace
        float* part = (float*)((char*)d_ws + WS_PART_OFF);
        hipLaunchKernelGGL((gemm_part_kernel<1>), dim3((ntok / TGB) * NKC), dim3(256), 0, stream,
                           x, whi, wlo, part, ntok);
        hipLaunchKernelGGL((finish_kernel<1>), dim3(ntok / 4), dim3(256), 0, stream,
                           part, bs, x, w, out, ntok);
    } else {
        // workspace too small: accumulate scores atomically in out's probs region
        hipLaunchKernelGGL(zero_kernel, dim3((ntok * NEXP) / 1024), dim3(256), 0, stream, out);
        hipLaunchKernelGGL((gemm_part_kernel<0>), dim3((ntok / TGB) * NKC), dim3(256), 0, stream,
                           x, whi, wlo, out, ntok);
        hipLaunchKernelGGL((finish_kernel<0>), dim3(ntok / 4), dim3(256), 0, stream,
                           out, bs, x, w, out, ntok);
    }
}